// Round 3
// baseline (232.111 us; speedup 1.0000x reference)
//
#include <hip/hip_runtime.h>

// Shapes
#define NB   256      // batch
#define E0   300      // embedding
#define EP   304      // padded embedding
#define F_   512      // features
#define KP   1536     // padded K (5*304=1520 -> 48*32)
#define NKT  48       // K-steps of 32
#define LQ_  64
#define LA_  256

typedef __attribute__((ext_vector_type(4))) float f32x4;
typedef __attribute__((ext_vector_type(8))) short short8;

#define XQ_ELEMS (NB * (LQ_ + 4) * EP)   // 5,292,032
#define XA_ELEMS (NB * (LA_ + 4) * EP)   // 20,234,240
#define OUTQ_ELEMS ((size_t)NB * F_ * LQ_)

__device__ __forceinline__ unsigned short f2bf(float x) {
    unsigned int u = __float_as_uint(x);
    u = u + 0x7fffu + ((u >> 16) & 1u);   // RNE
    return (unsigned short)(u >> 16);
}

// Build zero-padded bf16 x with halo: xp[b][lp][e], lp in [0,L+4), e in [0,304)
__global__ void prep_x(const float* __restrict__ q, const float* __restrict__ a,
                       unsigned short* __restrict__ xq, unsigned short* __restrict__ xa)
{
    int row = blockIdx.x;
    const float* src;
    unsigned short* dst;
    bool valid;
    if (row < NB * (LQ_ + 4)) {
        int b = row / (LQ_ + 4), lp = row - b * (LQ_ + 4);
        dst = xq + (size_t)row * EP;
        valid = (lp >= 2 && lp < 2 + LQ_);
        src = q + ((size_t)b * LQ_ + (lp - 2)) * E0;
    } else {
        int r2 = row - NB * (LQ_ + 4);
        int b = r2 / (LA_ + 4), lp = r2 - b * (LA_ + 4);
        dst = xa + (size_t)r2 * EP;
        valid = (lp >= 2 && lp < 2 + LA_);
        src = a + ((size_t)b * LA_ + (lp - 2)) * E0;
    }
    for (int e = threadIdx.x; e < EP; e += blockDim.x) {
        float v = (valid && e < E0) ? src[e] : 0.f;
        dst[e] = f2bf(v);
    }
}

// Wt[f][k'] = W[j*300+e][f] for k'=j*304+e (e<300), else 0.
__global__ void prep_w(const float* __restrict__ W, unsigned short* __restrict__ wt)
{
    int idx = blockIdx.x * 256 + threadIdx.x;
    int f = idx / KP;
    int k = idx - f * KP;
    int j = k / EP;
    int e = k - j * EP;
    float v = (k < 5 * EP && e < E0) ? W[(size_t)(j * E0 + e) * F_ + f] : 0.f;
    wt[idx] = f2bf(v);
}

// 256x256 tile, 8 waves (2f x 4l), per-wave 128x64, BK=32, ring-4 LDS,
// 2-phase-per-K-step interleave (m201-style grain) + counted vmcnt (never 0
// in the main loop) + setprio around MFMA clusters.
__global__ __launch_bounds__(512, 2) void qa_gemm(
    const unsigned short* __restrict__ xq,
    const unsigned short* __restrict__ xa,
    const unsigned short* __restrict__ wt,
    const float* __restrict__ bias,
    float* __restrict__ out)
{
    // ring buffer: [4][ W 256x32 | Z 256x32 ] bf16 = 4 x 32 KB = 128 KB
    __shared__ __align__(16) unsigned short lds[4 * 16384];

    const int bid = blockIdx.x;
    const int wg  = (bid & 7) * 80 + (bid >> 3);   // XCD swizzle, 640 % 8 == 0

    const unsigned short* xp;
    float* ob;
    int Mbase, lsh, Lp, ftBase;
    if (wg < 128) {                 // question: 64 M-tiles x 2 f-tiles
        Mbase  = (wg >> 1) * 256;
        ftBase = (wg & 1) * 256;
        xp = xq; lsh = 6; Lp = LQ_ + 4;
        ob = out;
    } else {                        // answer: 256 M-tiles x 2 f-tiles
        const int id = wg - 128;
        Mbase  = (id >> 1) * 256;
        ftBase = (id & 1) * 256;
        xp = xa; lsh = 8; Lp = LA_ + 4;
        ob = out + OUTQ_ELEMS;
    }
    const int Lv = 1 << lsh;

    const int tid  = threadIdx.x;
    const int lane = tid & 63;
    const int wid  = tid >> 6;
    const int wf   = wid >> 2;      // f half   (0..1) -> 128 f rows
    const int wn   = wid & 3;       // l quarter(0..3) -> 64 l rows
    const int lq   = lane >> 4;
    const int lr   = lane & 15;

    // ---- staging geometry (verified r2): wave wid covers rows wid*32..+32
    const int s_c  = (lane & 3) ^ ((lane >> 3) & 3);   // inverse-swizzled src chunk
    const int sub  = lane >> 2;
    const int srow0 = (wid * 2 + 0) * 16 + sub;
    const int srow1 = (wid * 2 + 1) * 16 + sub;

    const unsigned short* gW0 = wt + (size_t)(ftBase + srow0) * KP + s_c * 8;
    const unsigned short* gW1 = wt + (size_t)(ftBase + srow1) * KP + s_c * 8;
    const int mr0 = Mbase + srow0, mr1 = Mbase + srow1;
    const unsigned short* gZ0 = xp + (size_t)((mr0 >> lsh) * Lp + (mr0 & (Lv - 1))) * EP + s_c * 8;
    const unsigned short* gZ1 = xp + (size_t)((mr1 >> lsh) * Lp + (mr1 & (Lv - 1))) * EP + s_c * 8;

    unsigned short* dW0 = &lds[0] + (wid * 2 + 0) * 512;
    unsigned short* dW1 = &lds[0] + (wid * 2 + 1) * 512;
    unsigned short* dZ0 = dW0 + 8192;
    unsigned short* dZ1 = dW1 + 8192;

#define GL(p, d) __builtin_amdgcn_global_load_lds(                                  \
        (const __attribute__((address_space(1))) void*)(p),                         \
        (__attribute__((address_space(3))) void*)(d), 16, 0, 0)

#define STAGE_W(T) do { const int rb = ((T) & 3) * 16384; const size_t ko = (size_t)(T) * 32; \
    GL(gW0 + ko, dW0 + rb); GL(gW1 + ko, dW1 + rb); } while (0)
#define STAGE_Z(T) do { const int rb = ((T) & 3) * 16384; const size_t ko = (size_t)(T) * 32; \
    GL(gZ0 + ko, dZ0 + rb); GL(gZ1 + ko, dZ1 + rb); } while (0)

    // ---- fragment read offsets (bytes), chunk-swizzled (verified r1/r2)
    const int cs = (lq ^ ((lr >> 1) & 3)) * 16;
    int woff[8], zoff[4];
#pragma unroll
    for (int m = 0; m < 8; ++m) woff[m] = (wf * 128 + m * 16 + lr) * 64 + cs;
#pragma unroll
    for (int n = 0; n < 4; ++n) zoff[n] = (wn * 64 + n * 16 + lr) * 64 + cs + 16384;

    f32x4 acc[8][4] = {};

    // One K-step = 2 phases. Phase A: read B-frags + A-frags m0-3, issue W-unit
    // stage of T+3, barrier, 16 MFMA. Phase B: read A-frags m4-7, issue Z-unit
    // stage, barrier, 16 MFMA. End-of-step: counted vmcnt + barrier (by caller).
#define KSTEP(T, DO_STAGE) do {                                                     \
    const char* bb = (const char*)&lds[((T) & 3) * 16384];                          \
    short8 afr[4], bfr[4];                                                          \
    _Pragma("unroll") for (int n = 0; n < 4; ++n) bfr[n] = *(const short8*)(bb + zoff[n]); \
    _Pragma("unroll") for (int m = 0; m < 4; ++m) afr[m] = *(const short8*)(bb + woff[m]); \
    if (DO_STAGE) { STAGE_W((T) + 3); }                                             \
    asm volatile("s_barrier\n\ts_waitcnt lgkmcnt(0)" ::: "memory");                 \
    __builtin_amdgcn_sched_barrier(0);                                              \
    __builtin_amdgcn_s_setprio(1);                                                  \
    _Pragma("unroll") for (int m = 0; m < 4; ++m)                                   \
    _Pragma("unroll") for (int n = 0; n < 4; ++n)                                   \
        acc[m][n] = __builtin_amdgcn_mfma_f32_16x16x32_bf16(afr[m], bfr[n], acc[m][n], 0, 0, 0); \
    __builtin_amdgcn_s_setprio(0);                                                  \
    __builtin_amdgcn_sched_barrier(0);                                              \
    _Pragma("unroll") for (int m = 0; m < 4; ++m) afr[m] = *(const short8*)(bb + woff[4 + m]); \
    if (DO_STAGE) { STAGE_Z((T) + 3); }                                             \
    asm volatile("s_barrier\n\ts_waitcnt lgkmcnt(0)" ::: "memory");                 \
    __builtin_amdgcn_sched_barrier(0);                                              \
    __builtin_amdgcn_s_setprio(1);                                                  \
    _Pragma("unroll") for (int m = 0; m < 4; ++m)                                   \
    _Pragma("unroll") for (int n = 0; n < 4; ++n)                                   \
        acc[4 + m][n] = __builtin_amdgcn_mfma_f32_16x16x32_bf16(afr[m], bfr[n], acc[4 + m][n], 0, 0, 0); \
    __builtin_amdgcn_s_setprio(0);                                                  \
    __builtin_amdgcn_sched_barrier(0);                                              \
} while (0)

    // prologue: stage tiles 0,1,2 (12 loads); retire tile 0 (leave 8 in flight)
    STAGE_W(0); STAGE_Z(0); STAGE_W(1); STAGE_Z(1); STAGE_W(2); STAGE_Z(2);
    asm volatile("s_waitcnt vmcnt(8)\n\ts_barrier" ::: "memory");

    for (int t = 0; t < 45; ++t) {
        KSTEP(t, 1);
        // retire tile t+1; stages of t+2,t+3 (8 loads) stay in flight
        asm volatile("s_waitcnt vmcnt(8)\n\ts_barrier" ::: "memory");
    }
    KSTEP(45, 0);
    asm volatile("s_waitcnt vmcnt(4)\n\ts_barrier" ::: "memory");   // retire 46
    KSTEP(46, 0);
    asm volatile("s_waitcnt vmcnt(0)\n\ts_barrier" ::: "memory");   // retire 47
    KSTEP(47, 0);

#undef KSTEP
#undef STAGE_W
#undef STAGE_Z
#undef GL

    // ---- epilogue: D row = f = lq*4+reg, col = l = lr (verified r1/r2)
#pragma unroll
    for (int ns = 0; ns < 4; ++ns) {
        const int m = Mbase + wn * 64 + ns * 16 + lr;
        const int b = m >> lsh;
        const int l = m & (Lv - 1);
        float* orow = ob + ((size_t)b * F_ << lsh) + l;
#pragma unroll
        for (int ms = 0; ms < 8; ++ms) {
            const int f0 = ftBase + wf * 128 + ms * 16 + lq * 4;
            const f32x4 v = acc[ms][ns];
#pragma unroll
            for (int r = 0; r < 4; ++r) {
                const int f = f0 + r;
                orow[(size_t)f << lsh] = v[r] + __ldg(&bias[f]);
            }
        }
    }
}

extern "C" void kernel_launch(void* const* d_in, const int* in_sizes, int n_in,
                              void* d_out, int out_size, void* d_ws, size_t ws_size,
                              hipStream_t stream)
{
    const float* q    = (const float*)d_in[0];
    const float* a    = (const float*)d_in[1];
    const float* W    = (const float*)d_in[2];
    const float* bias = (const float*)d_in[3];
    float* out = (float*)d_out;

    unsigned short* xq = (unsigned short*)d_ws;
    unsigned short* xa = xq + XQ_ELEMS;
    unsigned short* wt = xa + XA_ELEMS;
    // ws needed: (XQ+XA+WT)*2 = 52.6 MB
    // (xa's K-pad tail reads overrun ~30 B into wt's region: in-bounds, and the
    //  matching Wt columns are zero, so values are don't-care.)

    const int xrows = NB * (LQ_ + 4) + NB * (LA_ + 4);   // 83,968
    prep_x<<<xrows, 128, 0, stream>>>(q, a, xq, xa);
    prep_w<<<(F_ * KP) / 256, 256, 0, stream>>>(W, wt);
    qa_gemm<<<640, 512, 0, stream>>>(xq, xa, wt, bias, out);
}

// Round 4
// 167.496 us; speedup vs baseline: 1.3858x; 1.3858x over previous
//
#include <hip/hip_runtime.h>

// Shapes
#define NB   256      // batch
#define E0   300      // embedding
#define EP   304      // padded embedding
#define F_   512      // features
#define KP   1536     // padded K (5*304=1520 -> 48*32)
#define NKT  48       // K-steps of 32
#define LQ_  64
#define LA_  256

typedef __attribute__((ext_vector_type(4))) float f32x4;
typedef __attribute__((ext_vector_type(8))) short short8;

#define XQ_ELEMS (NB * (LQ_ + 4) * EP)   // 5,292,032
#define XA_ELEMS (NB * (LA_ + 4) * EP)   // 20,234,240
#define WF_ELEMS (F_ * KP)               // 786,432 (fragment-packed)
#define OUTQ_ELEMS ((size_t)NB * F_ * LQ_)

__device__ __forceinline__ unsigned short f2bf(float x) {
    unsigned int u = __float_as_uint(x);
    u = u + 0x7fffu + ((u >> 16) & 1u);   // RNE
    return (unsigned short)(u >> 16);
}

// Zero-padded bf16 x with halo, vectorized: float4 in -> 4 bf16 (8B) out.
__global__ void prep_x(const float* __restrict__ q, const float* __restrict__ a,
                       unsigned short* __restrict__ xq, unsigned short* __restrict__ xa)
{
    const int row = blockIdx.x;
    const int tid = threadIdx.x;
    if (tid >= 76) return;
    const float* src;
    unsigned short* dst;
    bool valid;
    if (row < NB * (LQ_ + 4)) {
        int b = row / (LQ_ + 4), lp = row - b * (LQ_ + 4);
        dst = xq + (size_t)row * EP;
        valid = (lp >= 2 && lp < 2 + LQ_);
        src = q + ((size_t)b * LQ_ + (lp - 2)) * E0;
    } else {
        int r2 = row - NB * (LQ_ + 4);
        int b = r2 / (LA_ + 4), lp = r2 - b * (LA_ + 4);
        dst = xa + (size_t)r2 * EP;
        valid = (lp >= 2 && lp < 2 + LA_);
        src = a + ((size_t)b * LA_ + (lp - 2)) * E0;
    }
    unsigned long long pk = 0ull;
    if (valid && tid < 75) {  // rows are 1200B-stride -> float4-aligned
        const float4 v = reinterpret_cast<const float4*>(src)[tid];
        pk = (unsigned long long)f2bf(v.x)
           | ((unsigned long long)f2bf(v.y) << 16)
           | ((unsigned long long)f2bf(v.z) << 32)
           | ((unsigned long long)f2bf(v.w) << 48);
    }
    *reinterpret_cast<unsigned long long*>(dst + (size_t)tid * 4) = pk;
}

// Fragment-packed W: chunk (tile16, kc) is 1024B holding the exact per-lane
// A-operand of mfma_16x16x32: lane holds f = tile16*16 + (lane&15),
// k' = kc*32 + (lane>>4)*8 + j.  (Matches the verified r1-r3 LDS-read frags.)
__global__ void prep_w2(const float* __restrict__ W, unsigned short* __restrict__ wfr)
{
    int idx = blockIdx.x * 256 + threadIdx.x;     // grid = 32*48*512 shorts
    int j    = idx & 7;
    int lane = (idx >> 3) & 63;
    int chunk = idx >> 9;
    int kc = chunk % NKT;
    int tile16 = chunk / NKT;
    int f  = tile16 * 16 + (lane & 15);
    int kp = kc * 32 + (lane >> 4) * 8 + j;
    int jj = kp / EP;
    int e  = kp - jj * EP;
    float v = (kp < 5 * EP && e < E0) ? W[(size_t)(jj * E0 + e) * F_ + f] : 0.f;
    wfr[idx] = f2bf(v);
}

// 256f x 128l tile, 4 waves (wave = 64f x 128l), BK=32.
// Z: ring-4 LDS via global_load_lds.  W: L2->reg, asm-loaded, ping-pong 1 ahead.
__global__ __launch_bounds__(256, 2) void qa_gemm(
    const unsigned short* __restrict__ xq,
    const unsigned short* __restrict__ xa,
    const unsigned short* __restrict__ wfr,
    const float* __restrict__ bias,
    float* __restrict__ out)
{
    __shared__ __align__(16) unsigned short lds[4 * 4096];   // 32 KB Z-ring

    const int bid = blockIdx.x;
    const int wg  = (bid & 7) * 160 + (bid >> 3);   // XCD swizzle, 1280 % 8 == 0

    const unsigned short* xp;
    float* ob;
    int Mbase, lsh, Lp, ftBase;
    if (wg < 256) {                 // question: 128 M-tiles(128) x 2 f-halves
        Mbase  = (wg >> 1) * 128;
        ftBase = (wg & 1) * 256;
        xp = xq; lsh = 6; Lp = LQ_ + 4;
        ob = out;
    } else {                        // answer: 512 M-tiles x 2 f-halves
        const int id = wg - 256;
        Mbase  = (id >> 1) * 128;
        ftBase = (id & 1) * 256;
        xp = xa; lsh = 8; Lp = LA_ + 4;
        ob = out + OUTQ_ELEMS;
    }
    const int Lv = 1 << lsh;

    const int tid  = threadIdx.x;
    const int lane = tid & 63;
    const int wid  = tid >> 6;      // wave = f-slice (0..3)
    const int lq   = lane >> 4;
    const int lr   = lane & 15;

    // ---- Z staging geometry (verified r1-r3): wave wid covers rows wid*32..+32
    const int s_c  = (lane & 3) ^ ((lane >> 3) & 3);
    const int sub  = lane >> 2;
    const int mr0 = Mbase + wid * 32 + sub, mr1 = mr0 + 16;
    const unsigned short* gZ0 = xp + (size_t)((mr0 >> lsh) * Lp + (mr0 & (Lv - 1))) * EP + s_c * 8;
    const unsigned short* gZ1 = xp + (size_t)((mr1 >> lsh) * Lp + (mr1 & (Lv - 1))) * EP + s_c * 8;
    const int dz0 = wid * 1024, dz1 = dz0 + 512;    // shorts

#define GLLDS(p, d) __builtin_amdgcn_global_load_lds(                               \
        (const __attribute__((address_space(1))) void*)(p),                         \
        (__attribute__((address_space(3))) void*)(d), 16, 0, 0)
#define STAGE_Z(T) do { const int rb = ((T) & 3) * 4096; const size_t ko = (size_t)(T) * 32; \
    GLLDS(gZ0 + ko, lds + dz0 + rb); GLLDS(gZ1 + ko, lds + dz1 + rb); } while (0)

    // ---- W fragment pointers (frag = 512 shorts; step t -> +512 shorts)
    const unsigned short* wpc0 = wfr + (size_t)((ftBase >> 4) + wid * 4 + 0) * NKT * 512 + lane * 8;
    const unsigned short* wpc1 = wfr + (size_t)((ftBase >> 4) + wid * 4 + 1) * NKT * 512 + lane * 8;
    const unsigned short* wpc2 = wfr + (size_t)((ftBase >> 4) + wid * 4 + 2) * NKT * 512 + lane * 8;
    const unsigned short* wpc3 = wfr + (size_t)((ftBase >> 4) + wid * 4 + 3) * NKT * 512 + lane * 8;

#define WLOAD(dst, p) do {                                                           \
    asm volatile("global_load_dwordx4 %0, %1, off" : "=v"(dst) : "v"(p) : "memory"); \
    (p) += 512; } while (0)

    // ---- Z fragment LDS offsets (bytes), chunk-swizzled (verified r1-r3)
    const int cs = (lq ^ ((lr >> 1) & 3)) * 16;
    int zoff[8];
#pragma unroll
    for (int n = 0; n < 8; ++n) zoff[n] = (n * 16 + lr) * 64 + cs;

    f32x4 acc[4][8] = {};
    short8 WA0, WA1, WA2, WA3, WB0, WB1, WB2, WB3;

#define MFMA(a, b, c) __builtin_amdgcn_mfma_f32_16x16x32_bf16((a), (b), (c), 0, 0, 0)

    // One K-step: phase A: read Z-frags n0-3, issue W(t+1) + Z(t+3), barrier,
    // wait lgkm + counted vmcnt (W(t) guaranteed), MFMA n0-3; phase B: read
    // n4-7, barrier, lgkm, MFMA n4-7.  End fence (counted) by caller.
#define KSTEP(T, C0, C1, C2, C3, N0, N1, N2, N3, DO_W, DO_Z, MIDW) do {             \
    const char* bb = (const char*)lds + ((T) & 3) * 8192;                           \
    short8 bA[4], bB[4];                                                            \
    _Pragma("unroll") for (int n = 0; n < 4; ++n) bA[n] = *(const short8*)(bb + zoff[n]); \
    if (DO_W) { WLOAD(N0, wpc0); WLOAD(N1, wpc1); WLOAD(N2, wpc2); WLOAD(N3, wpc3); } \
    if (DO_Z) { STAGE_Z((T) + 3); }                                                 \
    asm volatile("s_barrier\n\ts_waitcnt vmcnt(" #MIDW ") lgkmcnt(0)" ::: "memory"); \
    __builtin_amdgcn_sched_barrier(0);                                              \
    __builtin_amdgcn_s_setprio(1);                                                  \
    _Pragma("unroll") for (int n = 0; n < 4; ++n) {                                 \
        acc[0][n] = MFMA(C0, bA[n], acc[0][n]);                                     \
        acc[1][n] = MFMA(C1, bA[n], acc[1][n]);                                     \
        acc[2][n] = MFMA(C2, bA[n], acc[2][n]);                                     \
        acc[3][n] = MFMA(C3, bA[n], acc[3][n]);                                     \
    }                                                                               \
    __builtin_amdgcn_s_setprio(0);                                                  \
    __builtin_amdgcn_sched_barrier(0);                                              \
    _Pragma("unroll") for (int n = 0; n < 4; ++n) bB[n] = *(const short8*)(bb + zoff[4 + n]); \
    asm volatile("s_barrier\n\ts_waitcnt lgkmcnt(0)" ::: "memory");                 \
    __builtin_amdgcn_sched_barrier(0);                                              \
    __builtin_amdgcn_s_setprio(1);                                                  \
    _Pragma("unroll") for (int n = 0; n < 4; ++n) {                                 \
        acc[0][4 + n] = MFMA(C0, bB[n], acc[0][4 + n]);                             \
        acc[1][4 + n] = MFMA(C1, bB[n], acc[1][4 + n]);                             \
        acc[2][4 + n] = MFMA(C2, bB[n], acc[2][4 + n]);                             \
        acc[3][4 + n] = MFMA(C3, bB[n], acc[3][4 + n]);                             \
    }                                                                               \
    __builtin_amdgcn_s_setprio(0);                                                  \
    __builtin_amdgcn_sched_barrier(0);                                              \
} while (0)

#define ENDFENCE(N) asm volatile("s_waitcnt vmcnt(" #N ")\n\ts_barrier" ::: "memory")

    // Prologue: W(0) first, then Z(0..2).  vmcnt(4) retires W0+Z0 exactly.
    WLOAD(WA0, wpc0); WLOAD(WA1, wpc1); WLOAD(WA2, wpc2); WLOAD(WA3, wpc3);
    STAGE_Z(0); STAGE_Z(1); STAGE_Z(2);
    ENDFENCE(4);

    for (int i = 0; i < 22; ++i) {          // t = 0..43
        const int t = 2 * i;
        KSTEP(t,     WA0, WA1, WA2, WA3, WB0, WB1, WB2, WB3, 1, 1, 8);
        ENDFENCE(12);                       // Z(t+1) retired
        KSTEP(t + 1, WB0, WB1, WB2, WB3, WA0, WA1, WA2, WA3, 1, 1, 8);
        ENDFENCE(12);
    }
    KSTEP(44, WA0, WA1, WA2, WA3, WB0, WB1, WB2, WB3, 1, 1, 8);   // stages Z47, loads W45
    ENDFENCE(12);
    KSTEP(45, WB0, WB1, WB2, WB3, WA0, WA1, WA2, WA3, 1, 0, 6);   // loads W46
    ENDFENCE(10);
    KSTEP(46, WA0, WA1, WA2, WA3, WB0, WB1, WB2, WB3, 1, 0, 4);   // loads W47
    ENDFENCE(8);
    KSTEP(47, WB0, WB1, WB2, WB3, WA0, WA1, WA2, WA3, 0, 0, 0);

#undef KSTEP
#undef ENDFENCE
#undef WLOAD
#undef STAGE_Z
#undef GLLDS
#undef MFMA

    // ---- epilogue: D row = f = lq*4+reg, col = l = lr (verified r1-r3)
#pragma unroll
    for (int ns = 0; ns < 8; ++ns) {
        const int m = Mbase + ns * 16 + lr;
        const int b = m >> lsh;
        const int l = m & (Lv - 1);
        float* orow = ob + ((size_t)b * F_ << lsh) + l;
#pragma unroll
        for (int ms = 0; ms < 4; ++ms) {
            const int f0 = ftBase + wid * 64 + ms * 16 + lq * 4;
            const f32x4 v = acc[ms][ns];
#pragma unroll
            for (int r = 0; r < 4; ++r)
                orow[(size_t)(f0 + r) << lsh] = v[r] + __ldg(&bias[f0 + r]);
        }
    }
}

extern "C" void kernel_launch(void* const* d_in, const int* in_sizes, int n_in,
                              void* d_out, int out_size, void* d_ws, size_t ws_size,
                              hipStream_t stream)
{
    const float* q    = (const float*)d_in[0];
    const float* a    = (const float*)d_in[1];
    const float* W    = (const float*)d_in[2];
    const float* bias = (const float*)d_in[3];
    float* out = (float*)d_out;

    unsigned short* xq  = (unsigned short*)d_ws;
    unsigned short* xa  = xq + XQ_ELEMS;
    unsigned short* wfr = xa + XA_ELEMS;
    // ws needed: (XQ+XA+WF)*2 = 52.6 MB

    const int xrows = NB * (LQ_ + 4) + NB * (LA_ + 4);   // 83,968
    prep_x<<<xrows, 128, 0, stream>>>(q, a, xq, xa);
    prep_w2<<<WF_ELEMS / 256, 256, 0, stream>>>(W, wfr);
    qa_gemm<<<1280, 256, 0, stream>>>(xq, xa, wfr, bias, out);
}